// Round 15
// baseline (202.044 us; speedup 1.0000x reference)
//
#include <hip/hip_runtime.h>
#include <hip/hip_bf16.h>
#include <cmath>

// B=2, S=2048, E=1024, H=16, HD=64, ROT=64 (full-head RoPE)
#define SB 2048
#define EB 1024
#define NH 16
#define HD 64
#define KLOG 0.14391156831212788f   // ln(10000)/64
#define QSC 0.18033688011112042f    // 0.125 * log2(e): fold softmax scale + exp2 conv into q

typedef unsigned short u16;
typedef unsigned int u32;
typedef __attribute__((ext_vector_type(8))) short short8;  // 8 bf16 (4 VGPRs)
typedef __attribute__((ext_vector_type(4))) float f32x4;

__device__ __forceinline__ u16 f2b(float x) {
  __hip_bfloat16 h = __float2bfloat16(x);
  return *reinterpret_cast<u16*>(&h);
}

__device__ __forceinline__ float b2f(u16 v) {
  u32 x = (u32)v << 16;
  float f;
  __builtin_memcpy(&f, &x, 4);
  return f;
}

// pack two fp32 -> bf16 pair in one u32 (lo in low half)
__device__ __forceinline__ u32 pkb(float lo, float hi) {
#if __has_builtin(__builtin_amdgcn_cvt_pk_bf16_f32)
  auto v = __builtin_amdgcn_cvt_pk_bf16_f32(lo, hi);
  u32 r;
  __builtin_memcpy(&r, &v, 4);
  return r;
#else
  return (u32)f2b(lo) | ((u32)f2b(hi) << 16);
#endif
}

// async global->LDS, 16 B per lane; LDS side is wave-uniform base + lane*16.
__device__ __forceinline__ void gl_lds16(const u16* g, u16* l) {
  __builtin_amdgcn_global_load_lds(
      (const __attribute__((address_space(1))) unsigned int*)g,
      (__attribute__((address_space(3))) unsigned int*)l, 16, 0, 0);
}

// ---------------------------------------------------------------------------
// conv_all: fp32->bf16 for x, qkv_w, out_w + RoPE cos/sin table + mask->float
// bias (0 / -1e9).
// ---------------------------------------------------------------------------
#define CN1 (4096 * 1024 / 4)
#define CN2 (3072 * 1024 / 4)
#define CN3 (1024 * 1024 / 4)
#define CNS (CN1 + CN2 + CN3)
__global__ __launch_bounds__(256) void conv_all(
    const float* __restrict__ x, const float* __restrict__ w1,
    const float* __restrict__ w2, const int* __restrict__ mask,
    u16* __restrict__ xb, u16* __restrict__ wqb, u16* __restrict__ owb,
    float* __restrict__ ctab, float* __restrict__ stab,
    float* __restrict__ fbias) {
  int i = blockIdx.x * 256 + threadIdx.x;
  if (i < CNS) {
    const float* src;
    u16* dst;
    int j;
    if (i < CN1) { src = x; dst = xb; j = i; }
    else if (i < CN1 + CN2) { src = w1; dst = wqb; j = i - CN1; }
    else { src = w2; dst = owb; j = i - CN1 - CN2; }
    float4 v = ((const float4*)src)[j];
    ushort4 o;
    o.x = f2b(v.x); o.y = f2b(v.y); o.z = f2b(v.z); o.w = f2b(v.w);
    ((ushort4*)dst)[j] = o;
  } else {
    int j = i - CNS;
    if (j < SB * 32) {
      int pos = j >> 5, p = j & 31;
      float th = (float)pos * expf(-(float)(2 * p) * KLOG);
      float sn, cs;
      sincosf(th, &sn, &cs);
      ctab[j] = cs; stab[j] = sn;
    } else {
      int j2 = j - SB * 32;
      if (j2 < 2 * SB) fbias[j2] = mask[j2] ? 0.f : -1e9f;
    }
  }
}

// ---------------------------------------------------------------------------
// Kernel 1: qkv = x @ qkv_w^T (bf16 MFMA) + bias, fused RoPE.
// DBUF gl_lds16 staging, ONE barrier per K-tile (R12-attn pattern), 4-chunk
// XOR swizzle on the global address side; frag slot = quad^(l15&3).
// q: *QSC, row-major (B,H,S,HD). k: row-major. v: TRANSPOSED vt[bh][d][s].
// ---------------------------------------------------------------------------
__global__ __launch_bounds__(256, 4) void qkv_mfma_rope(
    const u16* __restrict__ A, const u16* __restrict__ Bw,
    const float* __restrict__ bias, const float* __restrict__ ctab,
    const float* __restrict__ stab, u16* __restrict__ qb,
    u16* __restrict__ kb, u16* __restrict__ vt) {
  __shared__ u16 As[2][4096];   // [buf][row*32 + slot*8], slot = chunk^(row&3)
  __shared__ u16 Bs[2][4096];

  const int t = threadIdx.x;
  const int lane = t & 63, wv = t >> 6;
  const int l15 = lane & 15, quad = lane >> 4;
  const int wm = wv >> 1, wn = wv & 1;
  const int m0 = blockIdx.x * 128;
  const int n0 = blockIdx.y * 128;

  // staging: wave wv covers strip rows [wv*32, wv*32+32), 2 calls x 16 rows;
  // lane i -> row i>>2, fetches global chunk (i&3)^((i>>2)&3)
  const int srow = lane >> 2;
  const int schunk = ((lane & 3) ^ (srow & 3)) * 8;
  const u16* ga0 = A + (size_t)(m0 + wv * 32 + srow) * 1024 + schunk;
  const u16* gb0 = Bw + (size_t)(n0 + wv * 32 + srow) * 1024 + schunk;
  const int fslot = (quad ^ (l15 & 3)) * 8;   // frag read slot (elems)

  // prologue: stage tile 0 -> buf 0
#pragma unroll
  for (int c = 0; c < 2; c++) {
    gl_lds16(ga0 + c * 16 * 1024, &As[0][(wv * 32 + c * 16) * 32]);
    gl_lds16(gb0 + c * 16 * 1024, &Bs[0][(wv * 32 + c * 16) * 32]);
  }

  f32x4 acc[4][4] = {};

  for (int it = 0; it < 32; it++) {
    const int bufi = it & 1;
    __syncthreads();  // vmcnt drain completes buf[bufi]

    if (it + 1 < 32) {
      int k0 = (it + 1) * 32;
#pragma unroll
      for (int c = 0; c < 2; c++) {
        gl_lds16(ga0 + c * 16 * 1024 + k0, &As[1 - bufi][(wv * 32 + c * 16) * 32]);
        gl_lds16(gb0 + c * 16 * 1024 + k0, &Bs[1 - bufi][(wv * 32 + c * 16) * 32]);
      }
    }

    short8 a[4], b[4];
#pragma unroll
    for (int mi = 0; mi < 4; mi++)
      a[mi] = *(const short8*)&As[bufi][(wm * 64 + mi * 16 + l15) * 32 + fslot];
#pragma unroll
    for (int ni = 0; ni < 4; ni++)
      b[ni] = *(const short8*)&Bs[bufi][(wn * 64 + ni * 16 + l15) * 32 + fslot];
#pragma unroll
    for (int mi = 0; mi < 4; mi++)
#pragma unroll
      for (int ni = 0; ni < 4; ni++)
        acc[mi][ni] = __builtin_amdgcn_mfma_f32_16x16x32_bf16(a[mi], b[ni], acc[mi][ni], 0, 0, 0);
  }
  __syncthreads();  // protect nothing-in-LDS; harmless (epilogue uses no LDS)

  const int n_base = n0 + wn * 64;
  const int which = n_base >> 10;  // 0=q 1=k 2=v (uniform per wave)
  float b4[4];
#pragma unroll
  for (int ni = 0; ni < 4; ni++) b4[ni] = bias[n_base + ni * 16 + l15];

  const int h = (n_base & 1023) >> 6;
  const int bb = m0 >> 11;  // batch (block-uniform)
  if (which < 2) {
    u16* dst = (which == 0) ? qb : kb;
#pragma unroll
    for (int mi = 0; mi < 4; mi++) {
#pragma unroll
      for (int r = 0; r < 4; r++) {
        int row = wm * 64 + mi * 16 + quad * 4 + r;
        int s = (m0 & 2047) + row;
        size_t obase = ((size_t)(bb * NH + h) * SB + s) * HD;
        const float* cp = ctab + (size_t)s * 32;
        const float* sp = stab + (size_t)s * 32;
#pragma unroll
        for (int ni = 0; ni < 4; ni++) {
          float v = acc[mi][ni][r] + b4[ni];
          int d = ni * 16 + l15;
          float pv = __shfl_xor(v, 1, 64);  // partner column d^1
          float c = cp[d >> 1];
          float sn_ = sp[d >> 1];
          v = v * c + pv * ((d & 1) ? sn_ : -sn_);
          if (which == 0) v *= QSC;
          dst[obase + d] = f2b(v);
        }
      }
    }
  } else {
    // v: transposed store vt[bh][d][s], packed uint2 over 4 consecutive s
    size_t tbase = (size_t)(bb * NH + h) * HD;
#pragma unroll
    for (int mi = 0; mi < 4; mi++) {
      int s0 = (m0 & 2047) + wm * 64 + mi * 16 + quad * 4;
#pragma unroll
      for (int ni = 0; ni < 4; ni++) {
        int d = ni * 16 + l15;
        u32 p0 = pkb(acc[mi][ni][0] + b4[ni], acc[mi][ni][1] + b4[ni]);
        u32 p1 = pkb(acc[mi][ni][2] + b4[ni], acc[mi][ni][3] + b4[ni]);
        uint2 pk = make_uint2(p0, p1);
        *(uint2*)&vt[(tbase + d) * SB + s0] = pk;
      }
    }
  }
}

// ---------------------------------------------------------------------------
// Kernel 2: flash attention, S^T, qh=2 + SPLIT-K(2). (R13/R14 winner.)
// ---------------------------------------------------------------------------
__global__ __launch_bounds__(512, 4) void attn_mfma(
    const u16* __restrict__ qb, const u16* __restrict__ kb,
    const u16* __restrict__ vt, const float* __restrict__ fbias,
    u16* __restrict__ po0, u16* __restrict__ po1, float* __restrict__ pl) {
  __shared__ u16 Ks[2][4096];      // [buf][row*64 + swizzled chunk*8]
  __shared__ u16 Vt[2][4096];
  __shared__ u32 Ps2[8][16][34];   // [wave][qrow l15][krow-pair (+2 pad)]

  const int bh = blockIdx.x, b = bh >> 4;
  const int q0 = blockIdx.y * 256;
  const int kz = blockIdx.z;
  const int t = threadIdx.x;
  const int lane = t & 63, wv = t >> 6;   // wv 0..7
  const int l15 = lane & 15, quad = lane >> 4;

  short8 bq[2][2];
#pragma unroll
  for (int qh = 0; qh < 2; qh++) {
    const u16* qp = qb + ((size_t)bh * SB + q0 + wv * 32 + qh * 16 + l15) * HD;
    bq[qh][0] = *(const short8*)&qp[quad * 8];
    bq[qh][1] = *(const short8*)&qp[32 + quad * 8];
  }

  const u16* kbase = kb + (size_t)bh * SB * HD + (size_t)kz * 1024 * HD;
  const u16* vbase = vt + (size_t)bh * HD * SB + kz * 1024;
  const float* fbase = fbias + b * SB + kz * 1024;

  const int srow = lane >> 3;
  const int schunk = ((lane & 7) ^ srow) * 8;   // global-side XOR chunk swizzle
  const int fslot = quad ^ (l15 & 7);           // frag slot base (kk=0)

  gl_lds16(kbase + (size_t)(wv * 8 + srow) * HD + schunk, &Ks[0][wv * 512]);
  gl_lds16(vbase + (size_t)(wv * 8 + srow) * SB + schunk, &Vt[0][wv * 512]);

  f32x4 o[2][4] = {};
  float l_i[2] = {0.f, 0.f};

  for (int kt = 0; kt < 16; kt++) {
    const int bufi = kt & 1;
    __syncthreads();  // vmcnt(0) drain before barrier completes buf[bufi]

    if (kt + 1 < 16) {
      size_t ko = (size_t)(kt + 1) * 64;
      gl_lds16(kbase + (ko + wv * 8 + srow) * HD + schunk, &Ks[1 - bufi][wv * 512]);
      gl_lds16(vbase + (size_t)(wv * 8 + srow) * SB + ko + schunk, &Vt[1 - bufi][wv * 512]);
    }

    // S^T: K frags read once, feed both qh
    f32x4 s0[4], s1[4];
#pragma unroll
    for (int mb = 0; mb < 4; mb++) {
      const u16* kr = &Ks[bufi][(mb * 16 + l15) * 64];
      short8 a0 = *(const short8*)&kr[fslot * 8];
      short8 a1 = *(const short8*)&kr[(fslot ^ 4) * 8];
      f32x4 z0 = {}, z1 = {};
      z0 = __builtin_amdgcn_mfma_f32_16x16x32_bf16(a0, bq[0][0], z0, 0, 0, 0);
      s0[mb] = __builtin_amdgcn_mfma_f32_16x16x32_bf16(a1, bq[0][1], z0, 0, 0, 0);
      z1 = __builtin_amdgcn_mfma_f32_16x16x32_bf16(a0, bq[1][0], z1, 0, 0, 0);
      s1[mb] = __builtin_amdgcn_mfma_f32_16x16x32_bf16(a1, bq[1][1], z1, 0, 0, 0);
    }

    // no-max softmax: p = exp2(s + bias), accumulate l in-lane
#pragma unroll
    for (int mb = 0; mb < 4; mb++) {
      f32x4 bias4 = *(const f32x4*)&fbase[kt * 64 + mb * 16 + quad * 4];
#pragma unroll
      for (int r = 0; r < 4; r++) {
        float p0 = __builtin_amdgcn_exp2f(s0[mb][r] + bias4[r]);
        float p1 = __builtin_amdgcn_exp2f(s1[mb][r] + bias4[r]);
        s0[mb][r] = p0; l_i[0] += p0;
        s1[mb][r] = p1; l_i[1] += p1;
      }
    }

    // P-transform qh=0 then qh=1 (wave-private Ps2 reuse, in-pipe ordered)
    short8 pb0[2], pb1[2];
#pragma unroll
    for (int mb = 0; mb < 4; mb++) {
      uint2 w2 = make_uint2(pkb(s0[mb][0], s0[mb][1]), pkb(s0[mb][2], s0[mb][3]));
      *(uint2*)&Ps2[wv][l15][8 * mb + 2 * quad] = w2;
    }
#pragma unroll
    for (int kk = 0; kk < 2; kk++)
      pb0[kk] = *(const short8*)&Ps2[wv][l15][kk * 16 + 4 * quad];
#pragma unroll
    for (int mb = 0; mb < 4; mb++) {
      uint2 w2 = make_uint2(pkb(s1[mb][0], s1[mb][1]), pkb(s1[mb][2], s1[mb][3]));
      *(uint2*)&Ps2[wv][l15][8 * mb + 2 * quad] = w2;
    }
#pragma unroll
    for (int kk = 0; kk < 2; kk++)
      pb1[kk] = *(const short8*)&Ps2[wv][l15][kk * 16 + 4 * quad];

    // PV: V frags read once, feed both qh
#pragma unroll
    for (int nb = 0; nb < 4; nb++) {
      const u16* vr = &Vt[bufi][(nb * 16 + l15) * 64];
      short8 v0 = *(const short8*)&vr[fslot * 8];
      short8 v1 = *(const short8*)&vr[(fslot ^ 4) * 8];
      o[0][nb] = __builtin_amdgcn_mfma_f32_16x16x32_bf16(v0, pb0[0], o[0][nb], 0, 0, 0);
      o[0][nb] = __builtin_amdgcn_mfma_f32_16x16x32_bf16(v1, pb0[1], o[0][nb], 0, 0, 0);
      o[1][nb] = __builtin_amdgcn_mfma_f32_16x16x32_bf16(v0, pb1[0], o[1][nb], 0, 0, 0);
      o[1][nb] = __builtin_amdgcn_mfma_f32_16x16x32_bf16(v1, pb1[1], o[1][nb], 0, 0, 0);
    }
  }

  // epilogue: per qh reduce l, store normalized partial O (bf16) + l
  u16* po = kz ? po1 : po0;
#pragma unroll
  for (int qh = 0; qh < 2; qh++) {
    float l = l_i[qh];
    l += __shfl_xor(l, 16, 64);
    l += __shfl_xor(l, 32, 64);
    float linv = 1.f / fmaxf(l, 1e-30f);
    int qrow = q0 + wv * 32 + qh * 16 + l15;
    size_t base = ((size_t)bh * SB + qrow) * HD;
#pragma unroll
    for (int nb = 0; nb < 4; nb++)
#pragma unroll
      for (int pr = 0; pr < 2; pr++) {
        int d = nb * 16 + quad * 4 + 2 * pr;
        *(u32*)&po[base + d] =
            pkb(o[qh][nb][2 * pr] * linv, o[qh][nb][2 * pr + 1] * linv);
      }
    if (quad == 0) pl[kz * (32 * SB) + bh * SB + qrow] = l;
  }
}

// ---------------------------------------------------------------------------
// Kernel 3: out = combine(po0,po1) @ out_w^T + out_b (bf16 MFMA, fp32 out).
// DBUF, one barrier/iter: A combined in regs post-barrier, ds_write at top of
// next iter (reg live range crosses no barrier); B via dbuf gl_lds16.
// Same 4-chunk XOR swizzle as qkv. 64x128 tile -> 512 blocks, BK=32.
// ---------------------------------------------------------------------------
__global__ __launch_bounds__(256, 4) void out_fused(
    const u16* __restrict__ po0, const u16* __restrict__ po1,
    const float* __restrict__ pl, const u16* __restrict__ Bw,
    const float* __restrict__ bias, float* __restrict__ out) {
  __shared__ u16 As[2][2048];   // [buf][row*32 + slot*8]
  __shared__ u16 Bs[2][4096];

  const int t = threadIdx.x;
  const int lane = t & 63, wv = t >> 6;
  const int l15 = lane & 15, quad = lane >> 4;
  const int wm = wv >> 1, wn = wv & 1;   // wave = 32(M) x 64(N) subtile
  const int m0 = blockIdx.x * 64;
  const int n0 = blockIdx.y * 128;

  // A-combine coords: thread t -> row ar (0..63), global chunk ac (0..3)
  const int ar = t >> 2, ac = t & 3;
  const int aslot = ac ^ (ar & 3);             // LDS slot for this chunk
  const int am = m0 + ar;
  const int ab = am >> 11, aqrow = am & 2047;

  // B staging (gl_lds16 + swizzle), same as qkv
  const int srow = lane >> 2;
  const int schunk = ((lane & 3) ^ (srow & 3)) * 8;
  const u16* gb0 = Bw + (size_t)(n0 + wv * 32 + srow) * 1024 + schunk;
  const int fslot = (quad ^ (l15 & 3)) * 8;

  // A-combine for tile `it` -> 4 packed u32
  auto combineA = [&](int it, u32* res) {
    int k0 = it * 32;
    int h = k0 >> 6;
    int d = (k0 & 32) + ac * 8;
    int bh = ab * 16 + h;
    float l0 = pl[bh * SB + aqrow];
    float l1 = pl[32 * SB + bh * SB + aqrow];
    float rinv = 1.f / fmaxf(l0 + l1, 1e-30f);
    float w0 = l0 * rinv, w1 = l1 * rinv;
    size_t off = ((size_t)bh * SB + aqrow) * HD + d;
    uint4 ua = *(const uint4*)&po0[off];
    uint4 ub = *(const uint4*)&po1[off];
    const u32* pa = (const u32*)&ua;
    const u32* pq = (const u32*)&ub;
#pragma unroll
    for (int j = 0; j < 4; j++) {
      float o0 = b2f((u16)(pa[j] & 0xffff)) * w0 + b2f((u16)(pq[j] & 0xffff)) * w1;
      float o1 = b2f((u16)(pa[j] >> 16)) * w0 + b2f((u16)(pq[j] >> 16)) * w1;
      res[j] = pkb(o0, o1);
    }
  };

  // prologue: A(0) in regs, B(0) -> buf0
  u32 ares[4];
  combineA(0, ares);
#pragma unroll
  for (int c = 0; c < 2; c++)
    gl_lds16(gb0 + c * 16 * 1024, &Bs[0][(wv * 32 + c * 16) * 32]);

  f32x4 acc[2][4] = {};

  for (int it = 0; it < 32; it++) {
    const int bufi = it & 1;
    *(uint4*)&As[bufi][ar * 32 + aslot * 8] = *(const uint4*)ares;
    __syncthreads();  // drains ds_write (lgkm) + B's gl_lds16 (vmcnt)

    if (it + 1 < 32) {
      int k0 = (it + 1) * 32;
#pragma unroll
      for (int c = 0; c < 2; c++)
        gl_lds16(gb0 + c * 16 * 1024 + k0, &Bs[1 - bufi][(wv * 32 + c * 16) * 32]);
      combineA(it + 1, ares);
    }

    short8 a[2], b[4];
#pragma unroll
    for (int mi = 0; mi < 2; mi++)
      a[mi] = *(const short8*)&As[bufi][(wm * 32 + mi * 16 + l15) * 32 + fslot];
#pragma unroll
    for (int ni = 0; ni < 4; ni++)
      b[ni] = *(const short8*)&Bs[bufi][(wn * 64 + ni * 16 + l15) * 32 + fslot];
#pragma unroll
    for (int mi = 0; mi < 2; mi++)
#pragma unroll
      for (int ni = 0; ni < 4; ni++)
        acc[mi][ni] = __builtin_amdgcn_mfma_f32_16x16x32_bf16(a[mi], b[ni], acc[mi][ni], 0, 0, 0);
  }

  float b4[4];
#pragma unroll
  for (int ni = 0; ni < 4; ni++) b4[ni] = bias[n0 + wn * 64 + ni * 16 + l15];
#pragma unroll
  for (int mi = 0; mi < 2; mi++)
#pragma unroll
    for (int r = 0; r < 4; r++) {
      int m = m0 + wm * 32 + mi * 16 + quad * 4 + r;
#pragma unroll
      for (int ni = 0; ni < 4; ni++)
        out[(size_t)m * 1024 + n0 + wn * 64 + ni * 16 + l15] = acc[mi][ni][r] + b4[ni];
    }
}

extern "C" void kernel_launch(void* const* d_in, const int* in_sizes, int n_in,
                              void* d_out, int out_size, void* d_ws, size_t ws_size,
                              hipStream_t stream) {
  const float* x     = (const float*)d_in[0];
  const int* mask    = (const int*)d_in[1];
  const float* qkv_w = (const float*)d_in[2];
  const float* qkv_b = (const float*)d_in[3];
  const float* out_w = (const float*)d_in[4];
  const float* out_b = (const float*)d_in[5];
  float* out = (float*)d_out;

  char* wsb = (char*)d_ws;
  u16* xb    = (u16*)wsb;                       // 8 MB (xb; reused as po0 after qkv)
  u16* wqb   = (u16*)(wsb + ( 8ull << 20));     // 6 MB
  u16* owb   = (u16*)(wsb + (14ull << 20));     // 2 MB
  u16* qb    = (u16*)(wsb + (16ull << 20));     // 8 MB (pre-scaled by QSC)
  u16* kb    = (u16*)(wsb + (24ull << 20));     // 8 MB
  u16* vtb   = (u16*)(wsb + (32ull << 20));     // 8 MB (V transposed [bh][d][s])
  u16* po1   = (u16*)(wsb + (48ull << 20));     // 8 MB (split-K half 1 partial)
  float* ctab  = (float*)(wsb + (56ull << 20));               // 256 KB cos
  float* stab  = (float*)(wsb + (56ull << 20) + (256u << 10)); // 256 KB sin
  float* fbias = (float*)(wsb + (56ull << 20) + (512u << 10)); // 16 KB mask bias
  float* pl    = (float*)(wsb + (56ull << 20) + (768u << 10)); // 512 KB partial l
  u16* po0   = xb;                              // aliases xb (free after qkv)

  dim3 blk(256);
  int convBlocks = (CNS + SB * 32 + 2 * SB + 255) / 256;
  hipLaunchKernelGGL(conv_all, dim3(convBlocks), blk, 0, stream,
                     x, qkv_w, out_w, mask, xb, wqb, owb, ctab, stab, fbias);

  hipLaunchKernelGGL(qkv_mfma_rope, dim3(32, 24), blk, 0, stream,
                     xb, wqb, qkv_b, ctab, stab, qb, kb, vtb);

  hipLaunchKernelGGL(attn_mfma, dim3(32, 8, 2), dim3(512), 0, stream,
                     qb, kb, vtb, fbias, po0, po1, pl);

  hipLaunchKernelGGL(out_fused, dim3(64, 8), blk, 0, stream,
                     po0, po1, pl, owb, out_b, out);
}

// Round 16
// 194.308 us; speedup vs baseline: 1.0398x; 1.0398x over previous
//
#include <hip/hip_runtime.h>
#include <hip/hip_bf16.h>
#include <cmath>

// B=2, S=2048, E=1024, H=16, HD=64, ROT=64 (full-head RoPE)
#define SB 2048
#define EB 1024
#define NH 16
#define HD 64
#define KLOG 0.14391156831212788f   // ln(10000)/64
#define QSC 0.18033688011112042f    // 0.125 * log2(e): fold softmax scale + exp2 conv into q

typedef unsigned short u16;
typedef unsigned int u32;
typedef __attribute__((ext_vector_type(8))) short short8;  // 8 bf16 (4 VGPRs)
typedef __attribute__((ext_vector_type(4))) float f32x4;

__device__ __forceinline__ u16 f2b(float x) {
  __hip_bfloat16 h = __float2bfloat16(x);
  return *reinterpret_cast<u16*>(&h);
}

__device__ __forceinline__ float b2f(u16 v) {
  u32 x = (u32)v << 16;
  float f;
  __builtin_memcpy(&f, &x, 4);
  return f;
}

// pack two fp32 -> bf16 pair in one u32 (lo in low half)
__device__ __forceinline__ u32 pkb(float lo, float hi) {
#if __has_builtin(__builtin_amdgcn_cvt_pk_bf16_f32)
  auto v = __builtin_amdgcn_cvt_pk_bf16_f32(lo, hi);
  u32 r;
  __builtin_memcpy(&r, &v, 4);
  return r;
#else
  return (u32)f2b(lo) | ((u32)f2b(hi) << 16);
#endif
}

// async global->LDS, 16 B per lane; LDS side is wave-uniform base + lane*16.
__device__ __forceinline__ void gl_lds16(const u16* g, u16* l) {
  __builtin_amdgcn_global_load_lds(
      (const __attribute__((address_space(1))) unsigned int*)g,
      (__attribute__((address_space(3))) unsigned int*)l, 16, 0, 0);
}

// ---------------------------------------------------------------------------
// conv_all: fp32->bf16 for x, qkv_w, out_w + RoPE cos/sin table + mask->float
// bias (0 / -1e9).
// ---------------------------------------------------------------------------
#define CN1 (4096 * 1024 / 4)
#define CN2 (3072 * 1024 / 4)
#define CN3 (1024 * 1024 / 4)
#define CNS (CN1 + CN2 + CN3)
__global__ __launch_bounds__(256) void conv_all(
    const float* __restrict__ x, const float* __restrict__ w1,
    const float* __restrict__ w2, const int* __restrict__ mask,
    u16* __restrict__ xb, u16* __restrict__ wqb, u16* __restrict__ owb,
    float* __restrict__ ctab, float* __restrict__ stab,
    float* __restrict__ fbias) {
  int i = blockIdx.x * 256 + threadIdx.x;
  if (i < CNS) {
    const float* src;
    u16* dst;
    int j;
    if (i < CN1) { src = x; dst = xb; j = i; }
    else if (i < CN1 + CN2) { src = w1; dst = wqb; j = i - CN1; }
    else { src = w2; dst = owb; j = i - CN1 - CN2; }
    float4 v = ((const float4*)src)[j];
    ushort4 o;
    o.x = f2b(v.x); o.y = f2b(v.y); o.z = f2b(v.z); o.w = f2b(v.w);
    ((ushort4*)dst)[j] = o;
  } else {
    int j = i - CNS;
    if (j < SB * 32) {
      int pos = j >> 5, p = j & 31;
      float th = (float)pos * expf(-(float)(2 * p) * KLOG);
      float sn, cs;
      sincosf(th, &sn, &cs);
      ctab[j] = cs; stab[j] = sn;
    } else {
      int j2 = j - SB * 32;
      if (j2 < 2 * SB) fbias[j2] = mask[j2] ? 0.f : -1e9f;
    }
  }
}

// ---------------------------------------------------------------------------
// Kernel 1: qkv = x @ qkv_w^T (bf16 MFMA) + bias, fused RoPE. (R14 body.)
// XCD-GROUP SWIZZLE: 1-D grid of 768; assuming XCD = bid%8, each XCD gets an
// (8 m-block x 12 n-block) group -> per-XCD L2 working set 2 MB A + 3 MB B
// = 5 MB (vs 7 MB under the natural map, which thrashes the 4 MB L2).
// q: *QSC, row-major (B,H,S,HD). k: row-major. v: TRANSPOSED vt[bh][d][s].
// ---------------------------------------------------------------------------
__global__ __launch_bounds__(256, 4) void qkv_mfma_rope(
    const u16* __restrict__ A, const u16* __restrict__ Bw,
    const float* __restrict__ bias, const float* __restrict__ ctab,
    const float* __restrict__ stab, u16* __restrict__ qb,
    u16* __restrict__ kb, u16* __restrict__ vt) {
  __shared__ u16 As[128 * 32];   // contiguous == global order (gl_lds16)
  __shared__ u16 Bs[128 * 32];

  const int t = threadIdx.x;
  const int lane = t & 63, wv = t >> 6;
  const int l15 = lane & 15, quad = lane >> 4;
  const int wm = wv >> 1, wn = wv & 1;

  // XCD-group decode: bid%8 = XCD; group gi = 1 m-group(8 blks) x 4 n-groups
  const int bid = blockIdx.x;
  const int xcd = bid & 7, seq = bid >> 3;
  const int gi = xcd + 8 * (seq / 24);   // 0..31
  const int wi = seq % 24;               // 0..23 within group (8m x 3n)
  const int m0 = ((gi & 3) * 8 + (wi & 7)) * 128;
  const int n0 = (((gi >> 2) * 3) + (wi >> 3)) * 128;

  f32x4 acc[4][4] = {};

  for (int k0 = 0; k0 < 1024; k0 += 32) {
#pragma unroll
    for (int c = 0; c < 2; c++) {
      int r = wv * 32 + c * 16;
      const u16* ga = A + (size_t)(m0 + r + (lane >> 2)) * 1024 + k0 + (lane & 3) * 8;
      const u16* gb = Bw + (size_t)(n0 + r + (lane >> 2)) * 1024 + k0 + (lane & 3) * 8;
      gl_lds16(ga, &As[r * 32]);
      gl_lds16(gb, &Bs[r * 32]);
    }
    __syncthreads();

    short8 a[4], b[4];
#pragma unroll
    for (int mi = 0; mi < 4; mi++)
      a[mi] = *(const short8*)&As[(wm * 64 + mi * 16 + l15) * 32 + quad * 8];
#pragma unroll
    for (int ni = 0; ni < 4; ni++)
      b[ni] = *(const short8*)&Bs[(wn * 64 + ni * 16 + l15) * 32 + quad * 8];
#pragma unroll
    for (int mi = 0; mi < 4; mi++)
#pragma unroll
      for (int ni = 0; ni < 4; ni++)
        acc[mi][ni] = __builtin_amdgcn_mfma_f32_16x16x32_bf16(a[mi], b[ni], acc[mi][ni], 0, 0, 0);
    __syncthreads();
  }

  const int n_base = n0 + wn * 64;
  const int which = n_base >> 10;  // 0=q 1=k 2=v (uniform per wave)
  float b4[4];
#pragma unroll
  for (int ni = 0; ni < 4; ni++) b4[ni] = bias[n_base + ni * 16 + l15];

  const int h = (n_base & 1023) >> 6;
  const int bb = m0 >> 11;  // batch (block-uniform)
  if (which < 2) {
    u16* dst = (which == 0) ? qb : kb;
#pragma unroll
    for (int mi = 0; mi < 4; mi++) {
#pragma unroll
      for (int r = 0; r < 4; r++) {
        int row = wm * 64 + mi * 16 + quad * 4 + r;
        int s = (m0 & 2047) + row;
        size_t obase = ((size_t)(bb * NH + h) * SB + s) * HD;
        const float* cp = ctab + (size_t)s * 32;
        const float* sp = stab + (size_t)s * 32;
#pragma unroll
        for (int ni = 0; ni < 4; ni++) {
          float v = acc[mi][ni][r] + b4[ni];
          int d = ni * 16 + l15;
          float pv = __shfl_xor(v, 1, 64);  // partner column d^1
          float c = cp[d >> 1];
          float sn_ = sp[d >> 1];
          v = v * c + pv * ((d & 1) ? sn_ : -sn_);
          if (which == 0) v *= QSC;
          dst[obase + d] = f2b(v);
        }
      }
    }
  } else {
    // v: transposed store vt[bh][d][s], packed uint2 over 4 consecutive s
    size_t tbase = (size_t)(bb * NH + h) * HD;
#pragma unroll
    for (int mi = 0; mi < 4; mi++) {
      int s0 = (m0 & 2047) + wm * 64 + mi * 16 + quad * 4;
#pragma unroll
      for (int ni = 0; ni < 4; ni++) {
        int d = ni * 16 + l15;
        u32 p0 = pkb(acc[mi][ni][0] + b4[ni], acc[mi][ni][1] + b4[ni]);
        u32 p1 = pkb(acc[mi][ni][2] + b4[ni], acc[mi][ni][3] + b4[ni]);
        uint2 pk = make_uint2(p0, p1);
        *(uint2*)&vt[(tbase + d) * SB + s0] = pk;
      }
    }
  }
}

// ---------------------------------------------------------------------------
// Kernel 2: flash attention, S^T, qh=2 + SPLIT-K(2). (R13/R14 winner.)
// ---------------------------------------------------------------------------
__global__ __launch_bounds__(512, 4) void attn_mfma(
    const u16* __restrict__ qb, const u16* __restrict__ kb,
    const u16* __restrict__ vt, const float* __restrict__ fbias,
    u16* __restrict__ po0, u16* __restrict__ po1, float* __restrict__ pl) {
  __shared__ u16 Ks[2][4096];      // [buf][row*64 + swizzled chunk*8]
  __shared__ u16 Vt[2][4096];
  __shared__ u32 Ps2[8][16][34];   // [wave][qrow l15][krow-pair (+2 pad)]

  const int bh = blockIdx.x, b = bh >> 4;
  const int q0 = blockIdx.y * 256;
  const int kz = blockIdx.z;
  const int t = threadIdx.x;
  const int lane = t & 63, wv = t >> 6;   // wv 0..7
  const int l15 = lane & 15, quad = lane >> 4;

  short8 bq[2][2];
#pragma unroll
  for (int qh = 0; qh < 2; qh++) {
    const u16* qp = qb + ((size_t)bh * SB + q0 + wv * 32 + qh * 16 + l15) * HD;
    bq[qh][0] = *(const short8*)&qp[quad * 8];
    bq[qh][1] = *(const short8*)&qp[32 + quad * 8];
  }

  const u16* kbase = kb + (size_t)bh * SB * HD + (size_t)kz * 1024 * HD;
  const u16* vbase = vt + (size_t)bh * HD * SB + kz * 1024;
  const float* fbase = fbias + b * SB + kz * 1024;

  const int srow = lane >> 3;
  const int schunk = ((lane & 7) ^ srow) * 8;   // global-side XOR chunk swizzle
  const int fslot = quad ^ (l15 & 7);           // frag slot base (kk=0)

  gl_lds16(kbase + (size_t)(wv * 8 + srow) * HD + schunk, &Ks[0][wv * 512]);
  gl_lds16(vbase + (size_t)(wv * 8 + srow) * SB + schunk, &Vt[0][wv * 512]);

  f32x4 o[2][4] = {};
  float l_i[2] = {0.f, 0.f};

  for (int kt = 0; kt < 16; kt++) {
    const int bufi = kt & 1;
    __syncthreads();  // vmcnt(0) drain before barrier completes buf[bufi]

    if (kt + 1 < 16) {
      size_t ko = (size_t)(kt + 1) * 64;
      gl_lds16(kbase + (ko + wv * 8 + srow) * HD + schunk, &Ks[1 - bufi][wv * 512]);
      gl_lds16(vbase + (size_t)(wv * 8 + srow) * SB + ko + schunk, &Vt[1 - bufi][wv * 512]);
    }

    // S^T: K frags read once, feed both qh
    f32x4 s0[4], s1[4];
#pragma unroll
    for (int mb = 0; mb < 4; mb++) {
      const u16* kr = &Ks[bufi][(mb * 16 + l15) * 64];
      short8 a0 = *(const short8*)&kr[fslot * 8];
      short8 a1 = *(const short8*)&kr[(fslot ^ 4) * 8];
      f32x4 z0 = {}, z1 = {};
      z0 = __builtin_amdgcn_mfma_f32_16x16x32_bf16(a0, bq[0][0], z0, 0, 0, 0);
      s0[mb] = __builtin_amdgcn_mfma_f32_16x16x32_bf16(a1, bq[0][1], z0, 0, 0, 0);
      z1 = __builtin_amdgcn_mfma_f32_16x16x32_bf16(a0, bq[1][0], z1, 0, 0, 0);
      s1[mb] = __builtin_amdgcn_mfma_f32_16x16x32_bf16(a1, bq[1][1], z1, 0, 0, 0);
    }

    // no-max softmax: p = exp2(s + bias), accumulate l in-lane
#pragma unroll
    for (int mb = 0; mb < 4; mb++) {
      f32x4 bias4 = *(const f32x4*)&fbase[kt * 64 + mb * 16 + quad * 4];
#pragma unroll
      for (int r = 0; r < 4; r++) {
        float p0 = __builtin_amdgcn_exp2f(s0[mb][r] + bias4[r]);
        float p1 = __builtin_amdgcn_exp2f(s1[mb][r] + bias4[r]);
        s0[mb][r] = p0; l_i[0] += p0;
        s1[mb][r] = p1; l_i[1] += p1;
      }
    }

    // P-transform qh=0 then qh=1 (wave-private Ps2 reuse, in-pipe ordered)
    short8 pb0[2], pb1[2];
#pragma unroll
    for (int mb = 0; mb < 4; mb++) {
      uint2 w2 = make_uint2(pkb(s0[mb][0], s0[mb][1]), pkb(s0[mb][2], s0[mb][3]));
      *(uint2*)&Ps2[wv][l15][8 * mb + 2 * quad] = w2;
    }
#pragma unroll
    for (int kk = 0; kk < 2; kk++)
      pb0[kk] = *(const short8*)&Ps2[wv][l15][kk * 16 + 4 * quad];
#pragma unroll
    for (int mb = 0; mb < 4; mb++) {
      uint2 w2 = make_uint2(pkb(s1[mb][0], s1[mb][1]), pkb(s1[mb][2], s1[mb][3]));
      *(uint2*)&Ps2[wv][l15][8 * mb + 2 * quad] = w2;
    }
#pragma unroll
    for (int kk = 0; kk < 2; kk++)
      pb1[kk] = *(const short8*)&Ps2[wv][l15][kk * 16 + 4 * quad];

    // PV: V frags read once, feed both qh
#pragma unroll
    for (int nb = 0; nb < 4; nb++) {
      const u16* vr = &Vt[bufi][(nb * 16 + l15) * 64];
      short8 v0 = *(const short8*)&vr[fslot * 8];
      short8 v1 = *(const short8*)&vr[(fslot ^ 4) * 8];
      o[0][nb] = __builtin_amdgcn_mfma_f32_16x16x32_bf16(v0, pb0[0], o[0][nb], 0, 0, 0);
      o[0][nb] = __builtin_amdgcn_mfma_f32_16x16x32_bf16(v1, pb0[1], o[0][nb], 0, 0, 0);
      o[1][nb] = __builtin_amdgcn_mfma_f32_16x16x32_bf16(v0, pb1[0], o[1][nb], 0, 0, 0);
      o[1][nb] = __builtin_amdgcn_mfma_f32_16x16x32_bf16(v1, pb1[1], o[1][nb], 0, 0, 0);
    }
  }

  // epilogue: per qh reduce l, store normalized partial O (bf16) + l
  u16* po = kz ? po1 : po0;
#pragma unroll
  for (int qh = 0; qh < 2; qh++) {
    float l = l_i[qh];
    l += __shfl_xor(l, 16, 64);
    l += __shfl_xor(l, 32, 64);
    float linv = 1.f / fmaxf(l, 1e-30f);
    int qrow = q0 + wv * 32 + qh * 16 + l15;
    size_t base = ((size_t)bh * SB + qrow) * HD;
#pragma unroll
    for (int nb = 0; nb < 4; nb++)
#pragma unroll
      for (int pr = 0; pr < 2; pr++) {
        int d = nb * 16 + quad * 4 + 2 * pr;
        *(u32*)&po[base + d] =
            pkb(o[qh][nb][2 * pr] * linv, o[qh][nb][2 * pr + 1] * linv);
      }
    if (quad == 0) pl[kz * (32 * SB) + bh * SB + qrow] = l;
  }
}

// ---------------------------------------------------------------------------
// Kernel 3: out = combine(po0,po1) @ out_w^T + out_b (bf16 MFMA, fp32 out).
// (R14 form.) Split-K combine FUSED into A-tile staging. Natural grid map
// already gives ~4 MB per-XCD working set (A slice 2 MB + B 2 MB).
// 64x128 tile -> 512 blocks (2/CU), BK=32.
// ---------------------------------------------------------------------------
__global__ __launch_bounds__(256) void out_fused(
    const u16* __restrict__ po0, const u16* __restrict__ po1,
    const float* __restrict__ pl, const u16* __restrict__ Bw,
    const float* __restrict__ bias, float* __restrict__ out) {
  __shared__ u16 As[64 * 32];
  __shared__ u16 Bs[128 * 32];

  const int t = threadIdx.x;
  const int lane = t & 63, wv = t >> 6;
  const int l15 = lane & 15, quad = lane >> 4;
  const int wm = wv >> 1, wn = wv & 1;   // wave = 32(M) x 64(N) subtile
  const int m0 = blockIdx.x * 64;
  const int n0 = blockIdx.y * 128;

  // A-staging coords: thread t -> row ar (0..63), 8-elem chunk ac (0..3)
  const int ar = t >> 2, ac = t & 3;
  const int am = m0 + ar;
  const int ab = am >> 11, aqrow = am & 2047;

  f32x4 acc[2][4] = {};

  for (int k0 = 0; k0 < 1024; k0 += 32) {
    // A: combine split-K partials -> As (ds_write_b128, conflict-free)
    {
      int h = k0 >> 6;                  // 32-elem chunk lies within one head
      int d = (k0 & 32) + ac * 8;
      int bh = ab * 16 + h;
      float l0 = pl[bh * SB + aqrow];
      float l1 = pl[32 * SB + bh * SB + aqrow];
      float rinv = 1.f / fmaxf(l0 + l1, 1e-30f);
      float w0 = l0 * rinv, w1 = l1 * rinv;
      size_t off = ((size_t)bh * SB + aqrow) * HD + d;
      uint4 ua = *(const uint4*)&po0[off];
      uint4 ub = *(const uint4*)&po1[off];
      const u32* pa = (const u32*)&ua;
      const u32* pq = (const u32*)&ub;
      u32 res[4];
#pragma unroll
      for (int j = 0; j < 4; j++) {
        float o0 = b2f((u16)(pa[j] & 0xffff)) * w0 + b2f((u16)(pq[j] & 0xffff)) * w1;
        float o1 = b2f((u16)(pa[j] >> 16)) * w0 + b2f((u16)(pq[j] >> 16)) * w1;
        res[j] = pkb(o0, o1);
      }
      *(uint4*)&As[ar * 32 + ac * 8] = *(const uint4*)res;
    }
    // B: async global->LDS
#pragma unroll
    for (int c = 0; c < 2; c++) {
      int r = wv * 32 + c * 16;
      const u16* gb = Bw + (size_t)(n0 + r + (lane >> 2)) * 1024 + k0 + (lane & 3) * 8;
      gl_lds16(gb, &Bs[r * 32]);
    }
    __syncthreads();

    short8 a[2], b[4];
#pragma unroll
    for (int mi = 0; mi < 2; mi++)
      a[mi] = *(const short8*)&As[(wm * 32 + mi * 16 + l15) * 32 + quad * 8];
#pragma unroll
    for (int ni = 0; ni < 4; ni++)
      b[ni] = *(const short8*)&Bs[(wn * 64 + ni * 16 + l15) * 32 + quad * 8];
#pragma unroll
    for (int mi = 0; mi < 2; mi++)
#pragma unroll
      for (int ni = 0; ni < 4; ni++)
        acc[mi][ni] = __builtin_amdgcn_mfma_f32_16x16x32_bf16(a[mi], b[ni], acc[mi][ni], 0, 0, 0);
    __syncthreads();
  }

  float b4[4];
#pragma unroll
  for (int ni = 0; ni < 4; ni++) b4[ni] = bias[n0 + wn * 64 + ni * 16 + l15];
#pragma unroll
  for (int mi = 0; mi < 2; mi++)
#pragma unroll
    for (int r = 0; r < 4; r++) {
      int m = m0 + wm * 32 + mi * 16 + quad * 4 + r;
#pragma unroll
      for (int ni = 0; ni < 4; ni++)
        out[(size_t)m * 1024 + n0 + wn * 64 + ni * 16 + l15] = acc[mi][ni][r] + b4[ni];
    }
}

extern "C" void kernel_launch(void* const* d_in, const int* in_sizes, int n_in,
                              void* d_out, int out_size, void* d_ws, size_t ws_size,
                              hipStream_t stream) {
  const float* x     = (const float*)d_in[0];
  const int* mask    = (const int*)d_in[1];
  const float* qkv_w = (const float*)d_in[2];
  const float* qkv_b = (const float*)d_in[3];
  const float* out_w = (const float*)d_in[4];
  const float* out_b = (const float*)d_in[5];
  float* out = (float*)d_out;

  char* wsb = (char*)d_ws;
  u16* xb    = (u16*)wsb;                       // 8 MB (xb; reused as po0 after qkv)
  u16* wqb   = (u16*)(wsb + ( 8ull << 20));     // 6 MB
  u16* owb   = (u16*)(wsb + (14ull << 20));     // 2 MB
  u16* qb    = (u16*)(wsb + (16ull << 20));     // 8 MB (pre-scaled by QSC)
  u16* kb    = (u16*)(wsb + (24ull << 20));     // 8 MB
  u16* vtb   = (u16*)(wsb + (32ull << 20));     // 8 MB (V transposed [bh][d][s])
  u16* po1   = (u16*)(wsb + (48ull << 20));     // 8 MB (split-K half 1 partial)
  float* ctab  = (float*)(wsb + (56ull << 20));               // 256 KB cos
  float* stab  = (float*)(wsb + (56ull << 20) + (256u << 10)); // 256 KB sin
  float* fbias = (float*)(wsb + (56ull << 20) + (512u << 10)); // 16 KB mask bias
  float* pl    = (float*)(wsb + (56ull << 20) + (768u << 10)); // 512 KB partial l
  u16* po0   = xb;                              // aliases xb (free after qkv)

  dim3 blk(256);
  int convBlocks = (CNS + SB * 32 + 2 * SB + 255) / 256;
  hipLaunchKernelGGL(conv_all, dim3(convBlocks), blk, 0, stream,
                     x, qkv_w, out_w, mask, xb, wqb, owb, ctab, stab, fbias);

  hipLaunchKernelGGL(qkv_mfma_rope, dim3(768), blk, 0, stream,
                     xb, wqb, qkv_b, ctab, stab, qb, kb, vtb);

  hipLaunchKernelGGL(attn_mfma, dim3(32, 8, 2), dim3(512), 0, stream,
                     qb, kb, vtb, fbias, po0, po1, pl);

  hipLaunchKernelGGL(out_fused, dim3(64, 8), blk, 0, stream,
                     po0, po1, pl, owb, out_b, out);
}